// Round 3
// baseline (1724.552 us; speedup 1.0000x reference)
//
#include <hip/hip_runtime.h>
#include <hip/hip_bf16.h>

#define NTOK 8192
#define DDIM 768
#define HDIM 3072
#define NEXP 8
#define MROWS (NTOK*2)

typedef float f32x4 __attribute__((ext_vector_type(4)));
typedef short bf16x8 __attribute__((ext_vector_type(8)));
typedef unsigned short u16x4 __attribute__((ext_vector_type(4)));

__device__ __forceinline__ unsigned short f2bf(float f) {
  union { float f; unsigned u; } v; v.f = f;
  unsigned r = v.u + 0x7fffu + ((v.u >> 16) & 1u);  // RN-even
  return (unsigned short)(r >> 16);
}

// async global->LDS, 16B per lane; LDS dest = wave-uniform base + lane*16
typedef __attribute__((address_space(3))) unsigned int* lds_ptr_t;
typedef const __attribute__((address_space(1))) unsigned int* gbl_ptr_t;
__device__ __forceinline__ void async16(const void* g, void* l) {
  __builtin_amdgcn_global_load_lds((gbl_ptr_t)g, (lds_ptr_t)l, 16, 0, 0);
}

// ---------------- gating: logits, softmax sums, top-2, scatter ----------------
__global__ __launch_bounds__(128) void gating_kernel(
    const float* __restrict__ x, const float* __restrict__ gw,
    const float* __restrict__ nw, const float* __restrict__ noise,
    int* counts, float* sums, int* tok_list, float* gate_list,
    int* tok_top, float* gate_top)
{
  __shared__ float s_gw[NEXP*DDIM];
  __shared__ float s_sums[NEXP];
  __shared__ float s_nw[NEXP];
  int tid = threadIdx.x;
  for (int i = tid; i < NEXP*DDIM/4; i += 128)
    ((f32x4*)s_gw)[i] = ((const f32x4*)gw)[i];
  if (tid < NEXP) { s_sums[tid] = 0.f; s_nw[tid] = nw[tid]; }
  __syncthreads();
  int t = blockIdx.x*128 + tid;
  float acc[NEXP];
  #pragma unroll
  for (int e = 0; e < NEXP; ++e) acc[e] = 0.f;
  const f32x4* xr = (const f32x4*)(x + (size_t)t*DDIM);
  for (int d4 = 0; d4 < DDIM/4; ++d4) {
    f32x4 xv = xr[d4];
    #pragma unroll
    for (int e = 0; e < NEXP; ++e) {
      f32x4 g = *(const f32x4*)&s_gw[e*DDIM + d4*4];
      acc[e] += xv.x*g.x + xv.y*g.y + xv.z*g.z + xv.w*g.w;
    }
  }
  float m = acc[0];
  #pragma unroll
  for (int e = 1; e < NEXP; ++e) m = fmaxf(m, acc[e]);
  float p[NEXP], s = 0.f;
  #pragma unroll
  for (int e = 0; e < NEXP; ++e) { p[e] = __expf(acc[e]-m); s += p[e]; }
  float inv = 1.f/s;
  #pragma unroll
  for (int e = 0; e < NEXP; ++e) atomicAdd(&s_sums[e], p[e]*inv);
  float ln[NEXP];
  #pragma unroll
  for (int e = 0; e < NEXP; ++e) ln[e] = acc[e] + noise[(size_t)t*NEXP+e]*s_nw[e];
  int i0 = 0; float v0 = ln[0];
  #pragma unroll
  for (int e = 1; e < NEXP; ++e) if (ln[e] > v0) { v0 = ln[e]; i0 = e; }
  int i1 = -1; float v1 = 0.f;
  #pragma unroll
  for (int e = 0; e < NEXP; ++e)
    if (e != i0 && (i1 < 0 || ln[e] > v1)) { v1 = ln[e]; i1 = e; }
  float e1 = __expf(v1 - v0);
  float g0 = 1.f/(1.f + e1);
  float g1 = e1*g0;
  int p0 = atomicAdd(&counts[i0], 1);
  tok_list[i0*NTOK + p0] = t; gate_list[i0*NTOK + p0] = g0;
  int p1 = atomicAdd(&counts[i1], 1);
  tok_list[i1*NTOK + p1] = t; gate_list[i1*NTOK + p1] = g1;
  tok_top[2*t] = i0; tok_top[2*t+1] = i1;
  gate_top[2*t] = g0; gate_top[2*t+1] = g1;
  __syncthreads();
  if (tid < NEXP) atomicAdd(&sums[tid], s_sums[tid]);
}

// ---------------- offsets prefix + load-balance loss ----------------
__global__ void finalize_kernel(const int* counts, const float* sums,
                                int* offsets, float* loss_out)
{
  if (threadIdx.x == 0) {
    int o = 0;
    #pragma unroll
    for (int e = 0; e < NEXP; ++e) { offsets[e] = o; o += counts[e]; }
    offsets[NEXP] = o;
    float l = 0.f;
    #pragma unroll
    for (int e = 0; e < NEXP; ++e) {
      float dv = sums[e]*(1.f/(float)NTOK) - 1.f/(float)NEXP;
      l += dv*dv;
    }
    loss_out[0] = l*(0.01f/(float)NEXP);
  }
}

// ---------------- x -> bf16 ----------------
__global__ __launch_bounds__(256) void cvt_x_kernel(const float* __restrict__ x,
                                                    unsigned short* __restrict__ xb)
{
  int i = blockIdx.x*256 + threadIdx.x;
  f32x4 v = ((const f32x4*)x)[i];
  u16x4 o; o.x = f2bf(v.x); o.y = f2bf(v.y); o.z = f2bf(v.z); o.w = f2bf(v.w);
  ((u16x4*)xb)[i] = o;
}

// ---------------- transpose+convert: src [E][R][C] f32 -> dst [E][C][R] bf16 ----
__global__ __launch_bounds__(256) void transpose_cvt_kernel(
    const float* __restrict__ src, unsigned short* __restrict__ dst, int R, int C)
{
  __shared__ unsigned short s[64*65];
  int e = blockIdx.z;
  int r0 = blockIdx.y*64, c0 = blockIdx.x*64;
  const float* sp = src + ((size_t)e*R + r0)*C + c0;
  unsigned short* dp = dst + ((size_t)e*C + c0)*R + r0;
  int t = threadIdx.x;
  #pragma unroll
  for (int i = 0; i < 16; ++i) {
    int idx = t + 256*i;
    int r = idx >> 6, c = idx & 63;
    s[c*65 + r] = f2bf(sp[(size_t)r*C + c]);
  }
  __syncthreads();
  #pragma unroll
  for (int i = 0; i < 16; ++i) {
    int idx = t + 256*i;
    int c = idx >> 6, r = idx & 63;
    dp[(size_t)c*R + r] = s[c*65 + r];
  }
}

// ---------------- compact per-expert lists into M=16384 rows ----------------
__global__ __launch_bounds__(256) void compact_kernel(
    const int* __restrict__ counts, const int* __restrict__ offsets,
    const int* __restrict__ tok_list, const float* __restrict__ gate_list,
    int* __restrict__ row_token, float* __restrict__ row_gate)
{
  int e = blockIdx.y;
  int pos = blockIdx.x*256 + threadIdx.x;
  if (pos < counts[e]) {
    int r = offsets[e] + pos;
    row_token[r] = tok_list[e*NTOK + pos];
    row_gate[r]  = gate_list[e*NTOK + pos];
  }
}

// ---------------- y init with gated biases (covers all outputs) ----------------
__global__ __launch_bounds__(256) void init_y_kernel(
    const int* __restrict__ tok_top, const float* __restrict__ gate_top,
    const float* __restrict__ bp, float* __restrict__ y)
{
  int i = blockIdx.x*256 + threadIdx.x;
  int t = i / (DDIM/4);
  int d4 = i % (DDIM/4);
  int e0 = tok_top[2*t], e1 = tok_top[2*t+1];
  float g0 = gate_top[2*t], g1 = gate_top[2*t+1];
  f32x4 b0 = ((const f32x4*)(bp + (size_t)e0*DDIM))[d4];
  f32x4 b1v = ((const f32x4*)(bp + (size_t)e1*DDIM))[d4];
  ((f32x4*)y)[i] = g0*b0 + g1*b1v;
}

// ---------------- FFN1: 256 rows x 128 h-cols, both matrices -------------------
// 512 thr = 8 waves = 4 row-groups x 2 col-groups. Per wave: 4 mt x 4 nt x 2 mats
// = 32 MFMA/k-step, acc 128 AGPR -> 2 waves/SIMD. LDS: A 16KB + B 16KB.
// XOR swizzle: LDS slot (r,s) holds k-seg s^(r&3); readers address q^(r&3).
__global__ __launch_bounds__(512, 2) void ffn1_mfma(
    const unsigned short* __restrict__ xb,
    const unsigned short* __restrict__ w1T, const unsigned short* __restrict__ w2T,
    const float* __restrict__ b1, const float* __restrict__ b2,
    const int* __restrict__ offsets, const int* __restrict__ row_token,
    unsigned short* __restrict__ h_buf, int h_base, int HC)
{
  int e = blockIdx.z;
  int r_lo = offsets[e];
  int rows_e = offsets[e+1] - r_lo;
  int bx = blockIdx.x;
  if (bx*256 >= rows_e) return;
  int r0 = r_lo + bx*256;
  int rows_valid = rows_e - bx*256; if (rows_valid > 256) rows_valid = 256;
  int h0 = h_base + blockIdx.y*128;

  __shared__ __align__(16) char sA[16384];
  __shared__ __align__(16) char sB[16384];
  __shared__ int s_tok[256];

  int tid = threadIdx.x;
  if (tid < 256) {
    int r = r0 + tid; if (r > MROWS-1) r = MROWS-1;
    s_tok[tid] = row_token[r];
  }
  __syncthreads();

  int lane = tid & 63, w = tid >> 6;
  int wr = w & 3, wcg = w >> 2;
  int l16 = lane & 15, quad = lane >> 4;
  int lr = lane >> 2, ls = lane & 3;
  int kseg = ls ^ (lr & 3);               // swizzled k-seg this lane fetches

  const unsigned short* gA0 = xb + (size_t)s_tok[w*16 + lr]*DDIM + kseg*8;
  const unsigned short* gA1 = xb + (size_t)s_tok[(8+w)*16 + lr]*DDIM + kseg*8;
  const unsigned short* gB1 = w1T + ((size_t)e*HDIM + h0 + w*16 + lr)*DDIM + kseg*8;
  const unsigned short* gB2 = w2T + ((size_t)e*HDIM + h0 + w*16 + lr)*DDIM + kseg*8;
  char* lA0 = sA + w*1024;
  char* lA1 = sA + (8+w)*1024;
  char* lB1 = sB + w*1024;          // w1 -> chunks 0..7 (cols 0..127)
  char* lB2 = sB + (8+w)*1024;      // w2 -> chunks 8..15

  f32x4 acc[2][4][4];
  #pragma unroll
  for (int m = 0; m < 2; ++m)
    #pragma unroll
    for (int i = 0; i < 4; ++i)
      #pragma unroll
      for (int j = 0; j < 4; ++j) acc[m][i][j] = (f32x4){0,0,0,0};

  int swz = (quad ^ (l16 & 3))*16 + l16*64;

  for (int k0 = 0; k0 < DDIM; k0 += 32) {
    async16(gA0 + k0, lA0);
    async16(gA1 + k0, lA1);
    async16(gB1 + k0, lB1);
    async16(gB2 + k0, lB2);
    __syncthreads();
    bf16x8 bfr[2][4];
    #pragma unroll
    for (int m = 0; m < 2; ++m)
      #pragma unroll
      for (int nt = 0; nt < 4; ++nt)
        bfr[m][nt] = *(const bf16x8*)(sB + (m*8 + wcg*4 + nt)*1024 + swz);
    #pragma unroll
    for (int mt = 0; mt < 4; ++mt) {
      bf16x8 af = *(const bf16x8*)(sA + (wr*4 + mt)*1024 + swz);
      #pragma unroll
      for (int m = 0; m < 2; ++m)
        #pragma unroll
        for (int nt = 0; nt < 4; ++nt)
          acc[m][mt][nt] = __builtin_amdgcn_mfma_f32_16x16x32_bf16(af, bfr[m][nt], acc[m][mt][nt], 0, 0, 0);
    }
    __syncthreads();
  }
  // SwiGLU epilogue; C/D layout: col=lane&15, row=quad*4+reg
  #pragma unroll
  for (int nt = 0; nt < 4; ++nt) {
    int col = h0 + wcg*64 + nt*16 + l16;
    float bb1 = b1[(size_t)e*HDIM + col];
    float bb2 = b2[(size_t)e*HDIM + col];
    int cl = col - h_base;
    #pragma unroll
    for (int mt = 0; mt < 4; ++mt) {
      #pragma unroll
      for (int r = 0; r < 4; ++r) {
        int row = wr*64 + mt*16 + quad*4 + r;
        if (row < rows_valid) {
          float c1 = acc[0][mt][nt][r] + bb1;
          float c2 = acc[1][mt][nt][r] + bb2;
          float hv = c1 * (c2 / (1.f + __expf(-c2)));
          h_buf[(size_t)(r0 + row)*HC + cl] = f2bf(hv);
        }
      }
    }
  }
}

// ---------------- FFN2: 256 rows x 128 d-cols, y += gate*(h @ wp) --------------
// 256 thr = 4 row-waves. Per wave: 4 mt x 8 nt = 32 MFMA/k-step, acc 128 AGPR.
// LDS: A 16KB + B 8KB -> 2 blocks/CU.
__global__ __launch_bounds__(256, 2) void ffn2_mfma(
    const unsigned short* __restrict__ h_buf, const unsigned short* __restrict__ wpT,
    const int* __restrict__ offsets, const int* __restrict__ row_token,
    const float* __restrict__ row_gate, float* __restrict__ y, int h_base, int HC)
{
  int e = blockIdx.z;
  int r_lo = offsets[e];
  int rows_e = offsets[e+1] - r_lo;
  int bx = blockIdx.x;
  if (bx*256 >= rows_e) return;
  int r0 = r_lo + bx*256;
  int rows_valid = rows_e - bx*256; if (rows_valid > 256) rows_valid = 256;
  int c0 = blockIdx.y*128;

  __shared__ __align__(16) char sA[16384];
  __shared__ __align__(16) char sB[8192];
  __shared__ int s_tok[256];
  __shared__ float s_gate[256];

  int tid = threadIdx.x;
  {
    int r = r0 + tid; if (r > MROWS-1) r = MROWS-1;
    s_tok[tid]  = row_token[r];
    s_gate[tid] = row_gate[r];
  }
  __syncthreads();

  int lane = tid & 63, w = tid >> 6;
  int l16 = lane & 15, quad = lane >> 4;
  int lr = lane >> 2, ls = lane & 3;
  int kseg = ls ^ (lr & 3);

  // A: 4 rounds, chunk = i*4+w, rows chunk*16+lr (rows may be padded; clamp)
  const unsigned short* gA[4];
  #pragma unroll
  for (int i = 0; i < 4; ++i) {
    int rr = r0 + (i*4 + w)*16 + lr; if (rr > MROWS-1) rr = MROWS-1;
    gA[i] = h_buf + (size_t)rr*HC + kseg*8;
  }
  // B: 2 rounds, chunk = i*4+w, cols c0+chunk*16+lr
  const unsigned short* gB[2];
  #pragma unroll
  for (int i = 0; i < 2; ++i)
    gB[i] = wpT + ((size_t)e*DDIM + c0 + (i*4 + w)*16 + lr)*HDIM + h_base + kseg*8;

  f32x4 acc[4][8];
  #pragma unroll
  for (int i = 0; i < 4; ++i)
    #pragma unroll
    for (int j = 0; j < 8; ++j) acc[i][j] = (f32x4){0,0,0,0};

  int swz = (quad ^ (l16 & 3))*16 + l16*64;

  for (int k0 = 0; k0 < HC; k0 += 32) {
    #pragma unroll
    for (int i = 0; i < 4; ++i) async16(gA[i] + k0, sA + ((i*4 + w)*1024) + 0*(size_t)lane);
    #pragma unroll
    for (int i = 0; i < 2; ++i) async16(gB[i] + k0, sB + ((i*4 + w)*1024));
    __syncthreads();
    bf16x8 bfr[8];
    #pragma unroll
    for (int nt = 0; nt < 8; ++nt)
      bfr[nt] = *(const bf16x8*)(sB + nt*1024 + swz);
    #pragma unroll
    for (int mt = 0; mt < 4; ++mt) {
      bf16x8 af = *(const bf16x8*)(sA + (w*4 + mt)*1024 + swz);
      #pragma unroll
      for (int nt = 0; nt < 8; ++nt)
        acc[mt][nt] = __builtin_amdgcn_mfma_f32_16x16x32_bf16(af, bfr[nt], acc[mt][nt], 0, 0, 0);
    }
    __syncthreads();
  }
  #pragma unroll
  for (int nt = 0; nt < 8; ++nt) {
    int col = c0 + nt*16 + l16;
    #pragma unroll
    for (int mt = 0; mt < 4; ++mt) {
      #pragma unroll
      for (int r = 0; r < 4; ++r) {
        int row = w*64 + mt*16 + quad*4 + r;
        if (row < rows_valid)
          atomicAdd(&y[(size_t)s_tok[row]*DDIM + col], s_gate[row]*acc[mt][nt][r]);
      }
    }
  }
}

// ---------------- legacy FFN2 (fp32 B direct) — fallback when wpT doesn't fit --
__global__ __launch_bounds__(256) void ffn2_kernel(
    const unsigned short* __restrict__ h_buf, const float* __restrict__ wp,
    const int* __restrict__ offsets, const int* __restrict__ row_token,
    const float* __restrict__ row_gate, float* __restrict__ y, int h_base, int HC)
{
  int e = blockIdx.z;
  int r_lo = offsets[e];
  int rows_e = offsets[e+1] - r_lo;
  int bx = blockIdx.x;
  if (bx*128 >= rows_e) return;
  int r0 = r_lo + bx*128;
  int rows_valid = rows_e - bx*128; if (rows_valid > 128) rows_valid = 128;
  int c0 = blockIdx.y*128;

  __shared__ unsigned short sA[128*40];
  __shared__ int s_tok[128];
  __shared__ float s_gate[128];

  int tid = threadIdx.x;
  if (tid < 128) {
    int r = r0 + tid; if (r > MROWS-1) r = MROWS-1;
    s_tok[tid]  = row_token[r];
    s_gate[tid] = row_gate[r];
  }
  int lane = tid & 63;
  int wc = tid >> 6;
  int quad = lane >> 4, l16 = lane & 15;

  const float* wp0 = wp + (size_t)e*HDIM*DDIM + c0 + wc*32 + l16;

  f32x4 acc[8][2];
  #pragma unroll
  for (int i = 0; i < 8; ++i) { acc[i][0] = (f32x4){0,0,0,0}; acc[i][1] = (f32x4){0,0,0,0}; }
  __syncthreads();

  for (int k0 = 0; k0 < HC; k0 += 32) {
    #pragma unroll
    for (int i = 0; i < 2; ++i) {
      int c = i*256 + tid;
      int row = c >> 2, k8 = c & 3;
      int rr = r0 + row; if (rr > MROWS-1) rr = MROWS-1;
      bf16x8 v = *(const bf16x8*)(h_buf + (size_t)rr*HC + k0 + k8*8);
      *(bf16x8*)&sA[row*40 + k8*8] = v;
    }
    float bv[2][8];
    #pragma unroll
    for (int nt = 0; nt < 2; ++nt)
      #pragma unroll
      for (int j = 0; j < 8; ++j)
        bv[nt][j] = wp0[(size_t)(h_base + k0 + quad*8 + j)*DDIM + nt*16];
    bf16x8 bfr[2];
    #pragma unroll
    for (int nt = 0; nt < 2; ++nt)
      #pragma unroll
      for (int j = 0; j < 8; ++j) bfr[nt][j] = (short)f2bf(bv[nt][j]);
    __syncthreads();
    #pragma unroll
    for (int mt = 0; mt < 8; ++mt) {
      bf16x8 af = *(const bf16x8*)&sA[(mt*16 + l16)*40 + quad*8];
      acc[mt][0] = __builtin_amdgcn_mfma_f32_16x16x32_bf16(af, bfr[0], acc[mt][0], 0, 0, 0);
      acc[mt][1] = __builtin_amdgcn_mfma_f32_16x16x32_bf16(af, bfr[1], acc[mt][1], 0, 0, 0);
    }
    __syncthreads();
  }
  #pragma unroll
  for (int nt = 0; nt < 2; ++nt) {
    int col = c0 + wc*32 + nt*16 + l16;
    #pragma unroll
    for (int mt = 0; mt < 8; ++mt) {
      #pragma unroll
      for (int r = 0; r < 4; ++r) {
        int row = mt*16 + quad*4 + r;
        if (row < rows_valid)
          atomicAdd(&y[(size_t)s_tok[row]*DDIM + col], s_gate[row]*acc[mt][nt][r]);
      }
    }
  }
}

extern "C" void kernel_launch(void* const* d_in, const int* in_sizes, int n_in,
                              void* d_out, int out_size, void* d_ws, size_t ws_size,
                              hipStream_t stream)
{
  (void)in_sizes; (void)n_in; (void)out_size;
  const float* x     = (const float*)d_in[0];
  const float* gw    = (const float*)d_in[1];
  const float* nw    = (const float*)d_in[2];
  const float* noise = (const float*)d_in[3];
  const float* w1    = (const float*)d_in[4];
  const float* b1    = (const float*)d_in[5];
  const float* w2    = (const float*)d_in[6];
  const float* b2    = (const float*)d_in[7];
  const float* wp    = (const float*)d_in[8];
  const float* bp    = (const float*)d_in[9];
  float* y = (float*)d_out;

  char* ws = (char*)d_ws;
  int*   counts   = (int*)(ws + 0);
  float* sums     = (float*)(ws + 64);
  int*   offsets  = (int*)(ws + 128);
  size_t off = 256;
  int*   tok_list  = (int*)(ws + off);   off += (size_t)NEXP*NTOK*4;
  float* gate_list = (float*)(ws + off); off += (size_t)NEXP*NTOK*4;
  int*   tok_top   = (int*)(ws + off);   off += (size_t)NTOK*2*4;
  float* gate_top  = (float*)(ws + off); off += (size_t)NTOK*2*4;
  int*   row_token = (int*)(ws + off);   off += (size_t)MROWS*4;
  float* row_gate  = (float*)(ws + off); off += (size_t)MROWS*4;
  unsigned short* xb = (unsigned short*)(ws + off); off += (size_t)NTOK*DDIM*2;

  const size_t WT = (size_t)NEXP*DDIM*HDIM*2;   // one transposed bf16 weight set
  unsigned short* w1T = (unsigned short*)(ws + off);
  unsigned short* w2T = (unsigned short*)(ws + off + WT);
  unsigned short* wpT = (unsigned short*)(ws + off + 2*WT);
  bool haveP = (off + 3*WT + (size_t)MROWS*128*2 <= ws_size);
  size_t oH = off + (haveP ? 3*WT : 2*WT);

  static const int hc_opts[6] = {3072, 1536, 768, 384, 256, 128};
  int HC = 128;
  for (int i = 0; i < 6; ++i)
    if (oH + (size_t)MROWS*hc_opts[i]*2 <= ws_size) { HC = hc_opts[i]; break; }
  unsigned short* h_buf = (unsigned short*)(ws + oH);

  hipMemsetAsync(d_ws, 0, 256, stream);
  gating_kernel<<<NTOK/128, 128, 0, stream>>>(x, gw, nw, noise, counts, sums,
                                              tok_list, gate_list, tok_top, gate_top);
  finalize_kernel<<<1, 64, 0, stream>>>(counts, sums, offsets, y + (size_t)NTOK*DDIM);
  cvt_x_kernel<<<NTOK*DDIM/1024, 256, 0, stream>>>(x, xb);
  compact_kernel<<<dim3(NTOK/256, NEXP), 256, 0, stream>>>(counts, offsets, tok_list,
                                                           gate_list, row_token, row_gate);
  init_y_kernel<<<NTOK*DDIM/1024, 256, 0, stream>>>(tok_top, gate_top, bp, y);

  // weight transposes: w1/w2 [E][D][H] -> [E][H][D] bf16 ; wp [E][H][D] -> [E][D][H] bf16
  transpose_cvt_kernel<<<dim3(HDIM/64, DDIM/64, NEXP), 256, 0, stream>>>(w1, w1T, DDIM, HDIM);
  transpose_cvt_kernel<<<dim3(HDIM/64, DDIM/64, NEXP), 256, 0, stream>>>(w2, w2T, DDIM, HDIM);
  if (haveP)
    transpose_cvt_kernel<<<dim3(DDIM/64, HDIM/64, NEXP), 256, 0, stream>>>(wp, wpT, HDIM, DDIM);

  int nch = HDIM / HC;
  for (int c = 0; c < nch; ++c) {
    ffn1_mfma<<<dim3(32, HC/128, NEXP), 512, 0, stream>>>(xb, w1T, w2T, b1, b2, offsets,
                                                          row_token, h_buf, c*HC, HC);
    if (haveP)
      ffn2_mfma<<<dim3(32, DDIM/128, NEXP), 256, 0, stream>>>(h_buf, wpT, offsets, row_token,
                                                              row_gate, y, c*HC, HC);
    else
      ffn2_kernel<<<dim3(64, DDIM/128, NEXP), 256, 0, stream>>>(h_buf, wp, offsets, row_token,
                                                                row_gate, y, c*HC, HC);
  }
}

// Round 4
// 1005.952 us; speedup vs baseline: 1.7143x; 1.7143x over previous
//
#include <hip/hip_runtime.h>
#include <hip/hip_bf16.h>

#define NTOK 8192
#define DDIM 768
#define HDIM 3072
#define NEXP 8
#define MROWS (NTOK*2)

typedef float f32x4 __attribute__((ext_vector_type(4)));
typedef short bf16x8 __attribute__((ext_vector_type(8)));
typedef unsigned short u16x4 __attribute__((ext_vector_type(4)));

__device__ __forceinline__ unsigned short f2bf(float f) {
  union { float f; unsigned u; } v; v.f = f;
  unsigned r = v.u + 0x7fffu + ((v.u >> 16) & 1u);  // RN-even
  return (unsigned short)(r >> 16);
}

typedef __attribute__((address_space(3))) unsigned int* lds_ptr_t;
typedef const __attribute__((address_space(1))) unsigned int* gbl_ptr_t;
__device__ __forceinline__ void async16(const void* g, void* l) {
  __builtin_amdgcn_global_load_lds((gbl_ptr_t)g, (lds_ptr_t)l, 16, 0, 0);
}

// ---------------- gating ----------------
__global__ __launch_bounds__(128) void gating_kernel(
    const float* __restrict__ x, const float* __restrict__ gw,
    const float* __restrict__ nw, const float* __restrict__ noise,
    int* counts, float* sums, int* tok_list, float* gate_list,
    int* tok_top, float* gate_top, int* pos_top)
{
  __shared__ float s_gw[NEXP*DDIM];
  __shared__ float s_sums[NEXP];
  __shared__ float s_nw[NEXP];
  int tid = threadIdx.x;
  for (int i = tid; i < NEXP*DDIM/4; i += 128)
    ((f32x4*)s_gw)[i] = ((const f32x4*)gw)[i];
  if (tid < NEXP) { s_sums[tid] = 0.f; s_nw[tid] = nw[tid]; }
  __syncthreads();
  int t = blockIdx.x*128 + tid;
  float acc[NEXP];
  #pragma unroll
  for (int e = 0; e < NEXP; ++e) acc[e] = 0.f;
  const f32x4* xr = (const f32x4*)(x + (size_t)t*DDIM);
  for (int d4 = 0; d4 < DDIM/4; ++d4) {
    f32x4 xv = xr[d4];
    #pragma unroll
    for (int e = 0; e < NEXP; ++e) {
      f32x4 g = *(const f32x4*)&s_gw[e*DDIM + d4*4];
      acc[e] += xv.x*g.x + xv.y*g.y + xv.z*g.z + xv.w*g.w;
    }
  }
  float m = acc[0];
  #pragma unroll
  for (int e = 1; e < NEXP; ++e) m = fmaxf(m, acc[e]);
  float p[NEXP], s = 0.f;
  #pragma unroll
  for (int e = 0; e < NEXP; ++e) { p[e] = __expf(acc[e]-m); s += p[e]; }
  float inv = 1.f/s;
  #pragma unroll
  for (int e = 0; e < NEXP; ++e) atomicAdd(&s_sums[e], p[e]*inv);
  float ln[NEXP];
  #pragma unroll
  for (int e = 0; e < NEXP; ++e) ln[e] = acc[e] + noise[(size_t)t*NEXP+e]*s_nw[e];
  int i0 = 0; float v0 = ln[0];
  #pragma unroll
  for (int e = 1; e < NEXP; ++e) if (ln[e] > v0) { v0 = ln[e]; i0 = e; }
  int i1 = -1; float v1 = 0.f;
  #pragma unroll
  for (int e = 0; e < NEXP; ++e)
    if (e != i0 && (i1 < 0 || ln[e] > v1)) { v1 = ln[e]; i1 = e; }
  float e1 = __expf(v1 - v0);
  float g0 = 1.f/(1.f + e1);
  float g1 = e1*g0;
  int p0 = atomicAdd(&counts[i0], 1);
  tok_list[i0*NTOK + p0] = t; gate_list[i0*NTOK + p0] = g0;
  int p1 = atomicAdd(&counts[i1], 1);
  tok_list[i1*NTOK + p1] = t; gate_list[i1*NTOK + p1] = g1;
  tok_top[2*t] = i0; tok_top[2*t+1] = i1;
  gate_top[2*t] = g0; gate_top[2*t+1] = g1;
  pos_top[2*t] = p0; pos_top[2*t+1] = p1;
  __syncthreads();
  if (tid < NEXP) atomicAdd(&sums[tid], s_sums[tid]);
}

// ---------------- offsets prefix + load-balance loss ----------------
__global__ void finalize_kernel(const int* counts, const float* sums,
                                int* offsets, float* loss_out)
{
  if (threadIdx.x == 0) {
    int o = 0;
    #pragma unroll
    for (int e = 0; e < NEXP; ++e) { offsets[e] = o; o += counts[e]; }
    offsets[NEXP] = o;
    float l = 0.f;
    #pragma unroll
    for (int e = 0; e < NEXP; ++e) {
      float dv = sums[e]*(1.f/(float)NTOK) - 1.f/(float)NEXP;
      l += dv*dv;
    }
    loss_out[0] = l*(0.01f/(float)NEXP);
  }
}

// ---------------- x -> bf16 ----------------
__global__ __launch_bounds__(256) void cvt_x_kernel(const float* __restrict__ x,
                                                    unsigned short* __restrict__ xb)
{
  int i = blockIdx.x*256 + threadIdx.x;
  f32x4 v = ((const f32x4*)x)[i];
  u16x4 o; o.x = f2bf(v.x); o.y = f2bf(v.y); o.z = f2bf(v.z); o.w = f2bf(v.w);
  ((u16x4*)xb)[i] = o;
}

// -------- transpose+convert pair: z<NEXP -> (src1,dst1), else (src2,dst2) -------
__global__ __launch_bounds__(256) void transpose_cvt2_kernel(
    const float* __restrict__ src1, unsigned short* __restrict__ dst1,
    const float* __restrict__ src2, unsigned short* __restrict__ dst2,
    int R, int C)
{
  __shared__ unsigned short s[64*65];
  int z = blockIdx.z;
  int e = z & (NEXP-1);
  const float* src = (z < NEXP) ? src1 : src2;
  unsigned short* dst = (z < NEXP) ? dst1 : dst2;
  int r0 = blockIdx.y*64, c0 = blockIdx.x*64;
  const float* sp = src + ((size_t)e*R + r0)*C + c0;
  unsigned short* dp = dst + ((size_t)e*C + c0)*R + r0;
  int t = threadIdx.x;
  #pragma unroll
  for (int i = 0; i < 16; ++i) {
    int idx = t + 256*i;
    int r = idx >> 6, c = idx & 63;
    s[c*65 + r] = f2bf(sp[(size_t)r*C + c]);
  }
  __syncthreads();
  #pragma unroll
  for (int i = 0; i < 16; ++i) {
    int idx = t + 256*i;
    int c = idx >> 6, r = idx & 63;
    dp[(size_t)c*R + r] = s[c*65 + r];
  }
}

__global__ __launch_bounds__(256) void transpose_cvt_kernel(
    const float* __restrict__ src, unsigned short* __restrict__ dst, int R, int C)
{
  __shared__ unsigned short s[64*65];
  int e = blockIdx.z;
  int r0 = blockIdx.y*64, c0 = blockIdx.x*64;
  const float* sp = src + ((size_t)e*R + r0)*C + c0;
  unsigned short* dp = dst + ((size_t)e*C + c0)*R + r0;
  int t = threadIdx.x;
  #pragma unroll
  for (int i = 0; i < 16; ++i) {
    int idx = t + 256*i;
    int r = idx >> 6, c = idx & 63;
    s[c*65 + r] = f2bf(sp[(size_t)r*C + c]);
  }
  __syncthreads();
  #pragma unroll
  for (int i = 0; i < 16; ++i) {
    int idx = t + 256*i;
    int c = idx >> 6, r = idx & 63;
    dp[(size_t)c*R + r] = s[c*65 + r];
  }
}

// ---------------- compact per-expert lists into M=16384 rows ----------------
__global__ __launch_bounds__(256) void compact_kernel(
    const int* __restrict__ counts, const int* __restrict__ offsets,
    const int* __restrict__ tok_list, const float* __restrict__ gate_list,
    int* __restrict__ row_token, float* __restrict__ row_gate)
{
  int e = blockIdx.y;
  int pos = blockIdx.x*256 + threadIdx.x;
  if (pos < counts[e]) {
    int r = offsets[e] + pos;
    row_token[r] = tok_list[e*NTOK + pos];
    row_gate[r]  = gate_list[e*NTOK + pos];
  }
}

// ---------------- y init with gated biases (tier B/C only) ----------------
__global__ __launch_bounds__(256) void init_y_kernel(
    const int* __restrict__ tok_top, const float* __restrict__ gate_top,
    const float* __restrict__ bp, float* __restrict__ y)
{
  int i = blockIdx.x*256 + threadIdx.x;
  int t = i / (DDIM/4);
  int d4 = i % (DDIM/4);
  int e0 = tok_top[2*t], e1 = tok_top[2*t+1];
  float g0 = gate_top[2*t], g1 = gate_top[2*t+1];
  f32x4 b0 = ((const f32x4*)(bp + (size_t)e0*DDIM))[d4];
  f32x4 b1v = ((const f32x4*)(bp + (size_t)e1*DDIM))[d4];
  ((f32x4*)y)[i] = g0*b0 + g1*b1v;
}

// ---------------- FFN1: 128 rows x 64 h-cols (both mats), BK=64 ---------------
// 256 thr = 4 waves; wave w owns cols w*16..w*16+15 of both matrices.
// Per BK=64 step: 8 async16/wave, then 2x(8 af + 2 b reads, 16 MFMA). acc 64 AGPR.
// LDS: sA 16KB (16 slots: kh*8+rowchunk) + sB 16KB (kh*8+mat*4+colchunk(=w)).
__global__ __launch_bounds__(256) void ffn1_mfma(
    const unsigned short* __restrict__ xb,
    const unsigned short* __restrict__ w1T, const unsigned short* __restrict__ w2T,
    const float* __restrict__ b1, const float* __restrict__ b2,
    const int* __restrict__ offsets, const int* __restrict__ row_token,
    unsigned short* __restrict__ h_buf, int h_base, int HC)
{
  int e = blockIdx.z;
  int r_lo = offsets[e];
  int rows_e = offsets[e+1] - r_lo;
  int bx = blockIdx.x;
  if (bx*128 >= rows_e) return;
  int r0 = r_lo + bx*128;
  int rows_valid = rows_e - bx*128; if (rows_valid > 128) rows_valid = 128;
  int h0 = h_base + blockIdx.y*64;

  __shared__ __align__(16) char sA[16384];
  __shared__ __align__(16) char sB[16384];
  __shared__ int s_tok[128];

  int tid = threadIdx.x;
  if (tid < 128) {
    int r = r0 + tid; if (r > MROWS-1) r = MROWS-1;
    s_tok[tid] = row_token[r];
  }
  __syncthreads();

  int lane = tid & 63, w = tid >> 6;
  int l16 = lane & 15, quad = lane >> 4;
  int lr = lane >> 2, ls = lane & 3;

  // staging pointers: slot = i*4 + w
  const unsigned short* gA[4]; char* lA[4];
  const unsigned short* gB[4]; char* lB[4];
  #pragma unroll
  for (int i = 0; i < 4; ++i) {
    int slot = i*4 + w;
    int chunk = slot & 7, kh = slot >> 3;
    gA[i] = xb + (size_t)s_tok[chunk*16 + lr]*DDIM + kh*32 + ls*8;
    lA[i] = sA + slot*1024;
    int mat = (slot >> 2) & 1;   // colchunk = slot&3 == w
    int col = h0 + w*16 + lr;
    const unsigned short* base = mat ? w2T : w1T;
    gB[i] = base + ((size_t)e*HDIM + col)*DDIM + kh*32 + ls*8;
    lB[i] = sB + slot*1024;
  }

  f32x4 acc1[8], acc2[8];
  #pragma unroll
  for (int i = 0; i < 8; ++i) { acc1[i] = (f32x4){0,0,0,0}; acc2[i] = (f32x4){0,0,0,0}; }

  int fro = l16*64 + quad*16;    // frag read offset within a 1KB chunk

  for (int k0 = 0; k0 < DDIM; k0 += 64) {
    #pragma unroll
    for (int i = 0; i < 4; ++i) async16(gA[i] + k0, lA[i]);
    #pragma unroll
    for (int i = 0; i < 4; ++i) async16(gB[i] + k0, lB[i]);
    __syncthreads();
    #pragma unroll
    for (int kh = 0; kh < 2; ++kh) {
      bf16x8 bf1 = *(const bf16x8*)(sB + (kh*8 + w)*1024 + fro);
      bf16x8 bf2 = *(const bf16x8*)(sB + (kh*8 + 4 + w)*1024 + fro);
      #pragma unroll
      for (int mt = 0; mt < 8; ++mt) {
        bf16x8 af = *(const bf16x8*)(sA + (kh*8 + mt)*1024 + fro);
        acc1[mt] = __builtin_amdgcn_mfma_f32_16x16x32_bf16(af, bf1, acc1[mt], 0, 0, 0);
        acc2[mt] = __builtin_amdgcn_mfma_f32_16x16x32_bf16(af, bf2, acc2[mt], 0, 0, 0);
      }
    }
    __syncthreads();
  }
  // SwiGLU epilogue; C/D layout: col=lane&15, row=quad*4+reg
  int hcol = h0 + w*16 + l16;
  float bb1 = b1[(size_t)e*HDIM + hcol];
  float bb2 = b2[(size_t)e*HDIM + hcol];
  int hl = hcol - h_base;
  #pragma unroll
  for (int mt = 0; mt < 8; ++mt) {
    #pragma unroll
    for (int r = 0; r < 4; ++r) {
      int row = mt*16 + quad*4 + r;
      if (row < rows_valid) {
        float c1 = acc1[mt][r] + bb1;
        float c2 = acc2[mt][r] + bb2;
        float hv = c1 * (c2 / (1.f + __expf(-c2)));
        h_buf[(size_t)(r0 + row)*HC + hl] = f2bf(hv);
      }
    }
  }
}

// ---------------- FFN2: 128 rows x 128 d-cols, BK=64 ---------------------------
// 256 thr = 4 waves; wave w: rows (w&1)*64.., cols (w>>1)*64.. ; acc 64 AGPR.
// mode 0: store raw h@wp into part[M][DDIM] f32. mode 1: atomicAdd gated into y.
__global__ __launch_bounds__(256) void ffn2_mfma(
    const unsigned short* __restrict__ h_buf, const unsigned short* __restrict__ wpT,
    const int* __restrict__ offsets, const int* __restrict__ row_token,
    const float* __restrict__ row_gate, float* __restrict__ outp,
    int h_base, int HC, int mode)
{
  int e = blockIdx.z;
  int r_lo = offsets[e];
  int rows_e = offsets[e+1] - r_lo;
  int bx = blockIdx.x;
  if (bx*128 >= rows_e) return;
  int r0 = r_lo + bx*128;
  int rows_valid = rows_e - bx*128; if (rows_valid > 128) rows_valid = 128;
  int c0 = blockIdx.y*128;

  __shared__ __align__(16) char sA[16384];
  __shared__ __align__(16) char sB[16384];
  __shared__ int s_tok[128];
  __shared__ float s_gate[128];

  int tid = threadIdx.x;
  if (tid < 128) {
    int r = r0 + tid; if (r > MROWS-1) r = MROWS-1;
    s_tok[tid]  = row_token[r];
    s_gate[tid] = row_gate[r];
  }
  __syncthreads();

  int lane = tid & 63, w = tid >> 6;
  int l16 = lane & 15, quad = lane >> 4;
  int lr = lane >> 2, ls = lane & 3;
  int wr = w & 1, wcg = w >> 1;

  const unsigned short* gA[4]; char* lA[4];
  const unsigned short* gB[4]; char* lB[4];
  #pragma unroll
  for (int i = 0; i < 4; ++i) {
    int slot = i*4 + w;
    int chunk = slot & 7, kh = slot >> 3;
    int rr = r0 + chunk*16 + lr; if (rr > MROWS-1) rr = MROWS-1;
    gA[i] = h_buf + (size_t)rr*HC + kh*32 + ls*8;
    lA[i] = sA + slot*1024;
    int col = c0 + chunk*16 + lr;
    gB[i] = wpT + ((size_t)e*DDIM + col)*HDIM + h_base + kh*32 + ls*8;
    lB[i] = sB + slot*1024;
  }

  f32x4 acc[4][4];
  #pragma unroll
  for (int i = 0; i < 4; ++i)
    #pragma unroll
    for (int j = 0; j < 4; ++j) acc[i][j] = (f32x4){0,0,0,0};

  int fro = l16*64 + quad*16;

  for (int k0 = 0; k0 < HC; k0 += 64) {
    #pragma unroll
    for (int i = 0; i < 4; ++i) async16(gA[i] + k0, lA[i]);
    #pragma unroll
    for (int i = 0; i < 4; ++i) async16(gB[i] + k0, lB[i]);
    __syncthreads();
    #pragma unroll
    for (int kh = 0; kh < 2; ++kh) {
      bf16x8 bfr[4];
      #pragma unroll
      for (int nt = 0; nt < 4; ++nt)
        bfr[nt] = *(const bf16x8*)(sB + (kh*8 + wcg*4 + nt)*1024 + fro);
      #pragma unroll
      for (int mt = 0; mt < 4; ++mt) {
        bf16x8 af = *(const bf16x8*)(sA + (kh*8 + wr*4 + mt)*1024 + fro);
        #pragma unroll
        for (int nt = 0; nt < 4; ++nt)
          acc[mt][nt] = __builtin_amdgcn_mfma_f32_16x16x32_bf16(af, bfr[nt], acc[mt][nt], 0, 0, 0);
      }
    }
    __syncthreads();
  }

  if (mode == 0) {
    // raw store into part[M][DDIM]
    #pragma unroll
    for (int nt = 0; nt < 4; ++nt) {
      int col = c0 + wcg*64 + nt*16 + l16;
      #pragma unroll
      for (int mt = 0; mt < 4; ++mt) {
        #pragma unroll
        for (int r = 0; r < 4; ++r) {
          int row = wr*64 + mt*16 + quad*4 + r;
          if (row < rows_valid)
            outp[(size_t)(r0 + row)*DDIM + col] = acc[mt][nt][r];
        }
      }
    }
  } else {
    #pragma unroll
    for (int nt = 0; nt < 4; ++nt) {
      int col = c0 + wcg*64 + nt*16 + l16;
      #pragma unroll
      for (int mt = 0; mt < 4; ++mt) {
        #pragma unroll
        for (int r = 0; r < 4; ++r) {
          int row = wr*64 + mt*16 + quad*4 + r;
          if (row < rows_valid)
            atomicAdd(&outp[(size_t)s_tok[row]*DDIM + col], s_gate[row]*acc[mt][nt][r]);
        }
      }
    }
  }
}

// ---------------- combine (tier A): y = sum_i g_i*(part[row_i] + bp[e_i]) ------
__global__ __launch_bounds__(256) void combine_kernel(
    const float* __restrict__ part, const int* __restrict__ tok_top,
    const float* __restrict__ gate_top, const int* __restrict__ pos_top,
    const int* __restrict__ offsets, const float* __restrict__ bp,
    float* __restrict__ y)
{
  int i = blockIdx.x*256 + threadIdx.x;
  int t = i / (DDIM/4);
  int d4 = i % (DDIM/4);
  int e0 = tok_top[2*t], e1 = tok_top[2*t+1];
  float g0 = gate_top[2*t], g1 = gate_top[2*t+1];
  int r0 = offsets[e0] + pos_top[2*t];
  int r1 = offsets[e1] + pos_top[2*t+1];
  f32x4 v0 = ((const f32x4*)part)[(size_t)r0*(DDIM/4) + d4];
  f32x4 v1 = ((const f32x4*)part)[(size_t)r1*(DDIM/4) + d4];
  f32x4 b0 = ((const f32x4*)(bp + (size_t)e0*DDIM))[d4];
  f32x4 b1v = ((const f32x4*)(bp + (size_t)e1*DDIM))[d4];
  ((f32x4*)y)[i] = g0*(v0 + b0) + g1*(v1 + b1v);
}

// ---------------- legacy FFN2 (fp32 B direct) — tier C -------------------------
__global__ __launch_bounds__(256) void ffn2_kernel(
    const unsigned short* __restrict__ h_buf, const float* __restrict__ wp,
    const int* __restrict__ offsets, const int* __restrict__ row_token,
    const float* __restrict__ row_gate, float* __restrict__ y, int h_base, int HC)
{
  int e = blockIdx.z;
  int r_lo = offsets[e];
  int rows_e = offsets[e+1] - r_lo;
  int bx = blockIdx.x;
  if (bx*128 >= rows_e) return;
  int r0 = r_lo + bx*128;
  int rows_valid = rows_e - bx*128; if (rows_valid > 128) rows_valid = 128;
  int c0 = blockIdx.y*128;

  __shared__ unsigned short sA[128*40];
  __shared__ int s_tok[128];
  __shared__ float s_gate[128];

  int tid = threadIdx.x;
  if (tid < 128) {
    int r = r0 + tid; if (r > MROWS-1) r = MROWS-1;
    s_tok[tid]  = row_token[r];
    s_gate[tid] = row_gate[r];
  }
  int lane = tid & 63;
  int wc = tid >> 6;
  int quad = lane >> 4, l16 = lane & 15;

  const float* wp0 = wp + (size_t)e*HDIM*DDIM + c0 + wc*32 + l16;

  f32x4 acc[8][2];
  #pragma unroll
  for (int i = 0; i < 8; ++i) { acc[i][0] = (f32x4){0,0,0,0}; acc[i][1] = (f32x4){0,0,0,0}; }
  __syncthreads();

  for (int k0 = 0; k0 < HC; k0 += 32) {
    #pragma unroll
    for (int i = 0; i < 2; ++i) {
      int c = i*256 + tid;
      int row = c >> 2, k8 = c & 3;
      int rr = r0 + row; if (rr > MROWS-1) rr = MROWS-1;
      bf16x8 v = *(const bf16x8*)(h_buf + (size_t)rr*HC + k0 + k8*8);
      *(bf16x8*)&sA[row*40 + k8*8] = v;
    }
    float bv[2][8];
    #pragma unroll
    for (int nt = 0; nt < 2; ++nt)
      #pragma unroll
      for (int j = 0; j < 8; ++j)
        bv[nt][j] = wp0[(size_t)(h_base + k0 + quad*8 + j)*DDIM + nt*16];
    bf16x8 bfr[2];
    #pragma unroll
    for (int nt = 0; nt < 2; ++nt)
      #pragma unroll
      for (int j = 0; j < 8; ++j) bfr[nt][j] = (short)f2bf(bv[nt][j]);
    __syncthreads();
    #pragma unroll
    for (int mt = 0; mt < 8; ++mt) {
      bf16x8 af = *(const bf16x8*)&sA[(mt*16 + l16)*40 + quad*8];
      acc[mt][0] = __builtin_amdgcn_mfma_f32_16x16x32_bf16(af, bfr[0], acc[mt][0], 0, 0, 0);
      acc[mt][1] = __builtin_amdgcn_mfma_f32_16x16x32_bf16(af, bfr[1], acc[mt][1], 0, 0, 0);
    }
    __syncthreads();
  }
  #pragma unroll
  for (int nt = 0; nt < 2; ++nt) {
    int col = c0 + wc*32 + nt*16 + l16;
    #pragma unroll
    for (int mt = 0; mt < 8; ++mt) {
      #pragma unroll
      for (int r = 0; r < 4; ++r) {
        int row = mt*16 + quad*4 + r;
        if (row < rows_valid)
          atomicAdd(&y[(size_t)s_tok[row]*DDIM + col], s_gate[row]*acc[mt][nt][r]);
      }
    }
  }
}

extern "C" void kernel_launch(void* const* d_in, const int* in_sizes, int n_in,
                              void* d_out, int out_size, void* d_ws, size_t ws_size,
                              hipStream_t stream)
{
  (void)in_sizes; (void)n_in; (void)out_size;
  const float* x     = (const float*)d_in[0];
  const float* gw    = (const float*)d_in[1];
  const float* nw    = (const float*)d_in[2];
  const float* noise = (const float*)d_in[3];
  const float* w1    = (const float*)d_in[4];
  const float* b1    = (const float*)d_in[5];
  const float* w2    = (const float*)d_in[6];
  const float* b2    = (const float*)d_in[7];
  const float* wp    = (const float*)d_in[8];
  const float* bp    = (const float*)d_in[9];
  float* y = (float*)d_out;

  char* ws = (char*)d_ws;
  int*   counts   = (int*)(ws + 0);
  float* sums     = (float*)(ws + 64);
  int*   offsets  = (int*)(ws + 128);
  size_t off = 256;
  int*   tok_list  = (int*)(ws + off);   off += (size_t)NEXP*NTOK*4;
  float* gate_list = (float*)(ws + off); off += (size_t)NEXP*NTOK*4;
  int*   tok_top   = (int*)(ws + off);   off += (size_t)NTOK*2*4;
  float* gate_top  = (float*)(ws + off); off += (size_t)NTOK*2*4;
  int*   pos_top   = (int*)(ws + off);   off += (size_t)NTOK*2*4;
  int*   row_token = (int*)(ws + off);   off += (size_t)MROWS*4;
  float* row_gate  = (float*)(ws + off); off += (size_t)MROWS*4;
  unsigned short* xb = (unsigned short*)(ws + off); off += (size_t)NTOK*DDIM*2;

  const size_t WT    = (size_t)NEXP*DDIM*HDIM*2;   // one transposed bf16 weight set
  const size_t HFULL = (size_t)MROWS*HDIM*2;       // full h_buf bf16
  const size_t PSZ   = (size_t)MROWS*DDIM*4;       // part f32

  unsigned short* w1T = (unsigned short*)(ws + off);
  unsigned short* w2T = (unsigned short*)(ws + off + WT);
  unsigned short* wpT = (unsigned short*)(ws + off + 2*WT);

  bool tierA = (off + 3*WT + HFULL + PSZ <= ws_size);
  bool haveP = (off + 3*WT + (size_t)MROWS*128*2 <= ws_size);
  size_t oH = off + (haveP ? 3*WT : 2*WT);

  int HC;
  unsigned short* h_buf;
  float* part = nullptr;
  if (tierA) {
    HC = HDIM;
    h_buf = (unsigned short*)(ws + off + 3*WT);
    part  = (float*)(ws + off + 3*WT + HFULL);
  } else {
    static const int hc_opts[6] = {3072, 1536, 768, 384, 192, 128};
    HC = 128;
    for (int i = 0; i < 6; ++i)
      if (oH + (size_t)MROWS*hc_opts[i]*2 <= ws_size) { HC = hc_opts[i]; break; }
    h_buf = (unsigned short*)(ws + oH);
  }

  hipMemsetAsync(d_ws, 0, 256, stream);
  cvt_x_kernel<<<NTOK*DDIM/1024, 256, 0, stream>>>(x, xb);
  // w1/w2 [E][D][H] -> bf16 [E][H][D] (one launch), wp [E][H][D] -> bf16 [E][D][H]
  transpose_cvt2_kernel<<<dim3(HDIM/64, DDIM/64, NEXP*2), 256, 0, stream>>>(
      w1, w1T, w2, w2T, DDIM, HDIM);
  if (haveP)
    transpose_cvt_kernel<<<dim3(DDIM/64, HDIM/64, NEXP), 256, 0, stream>>>(wp, wpT, HDIM, DDIM);

  gating_kernel<<<NTOK/128, 128, 0, stream>>>(x, gw, nw, noise, counts, sums,
                                              tok_list, gate_list, tok_top, gate_top, pos_top);
  finalize_kernel<<<1, 64, 0, stream>>>(counts, sums, offsets, y + (size_t)NTOK*DDIM);
  compact_kernel<<<dim3(NTOK/256, NEXP), 256, 0, stream>>>(counts, offsets, tok_list,
                                                           gate_list, row_token, row_gate);

  if (tierA) {
    ffn1_mfma<<<dim3(128, HDIM/64, NEXP), 256, 0, stream>>>(xb, w1T, w2T, b1, b2, offsets,
                                                            row_token, h_buf, 0, HC);
    ffn2_mfma<<<dim3(128, DDIM/128, NEXP), 256, 0, stream>>>(h_buf, wpT, offsets, row_token,
                                                             row_gate, part, 0, HC, 0);
    combine_kernel<<<NTOK*DDIM/1024, 256, 0, stream>>>(part, tok_top, gate_top, pos_top,
                                                       offsets, bp, y);
  } else {
    init_y_kernel<<<NTOK*DDIM/1024, 256, 0, stream>>>(tok_top, gate_top, bp, y);
    int nch = HDIM / HC;
    for (int c = 0; c < nch; ++c) {
      ffn1_mfma<<<dim3(128, HC/64, NEXP), 256, 0, stream>>>(xb, w1T, w2T, b1, b2, offsets,
                                                            row_token, h_buf, c*HC, HC);
      if (haveP)
        ffn2_mfma<<<dim3(128, DDIM/128, NEXP), 256, 0, stream>>>(h_buf, wpT, offsets, row_token,
                                                                 row_gate, y, c*HC, HC, 1);
      else
        ffn2_kernel<<<dim3(128, DDIM/128, NEXP), 256, 0, stream>>>(h_buf, wp, offsets, row_token,
                                                                   row_gate, y, c*HC, HC);
    }
  }
}

// Round 5
// 823.772 us; speedup vs baseline: 2.0935x; 1.2212x over previous
//
#include <hip/hip_runtime.h>
#include <hip/hip_bf16.h>

#define NTOK 8192
#define DDIM 768
#define HDIM 3072
#define NEXP 8
#define MROWS (NTOK*2)
#define RBMAX 32

typedef float f32x4 __attribute__((ext_vector_type(4)));
typedef short bf16x8 __attribute__((ext_vector_type(8)));
typedef unsigned short u16x4 __attribute__((ext_vector_type(4)));

__device__ __forceinline__ unsigned short f2bf(float f) {
  union { float f; unsigned u; } v; v.f = f;
  unsigned r = v.u + 0x7fffu + ((v.u >> 16) & 1u);  // RN-even
  return (unsigned short)(r >> 16);
}

typedef __attribute__((address_space(3))) unsigned int* lds_ptr_t;
typedef const __attribute__((address_space(1))) unsigned int* gbl_ptr_t;
__device__ __forceinline__ void async16(const void* g, void* l) {
  __builtin_amdgcn_global_load_lds((gbl_ptr_t)g, (lds_ptr_t)l, 16, 0, 0);
}

// ---------------- gating ----------------
__global__ __launch_bounds__(128) void gating_kernel(
    const float* __restrict__ x, const float* __restrict__ gw,
    const float* __restrict__ nw, const float* __restrict__ noise,
    int* counts, float* sums, int* tok_list, float* gate_list,
    int* tok_top, float* gate_top, int* pos_top)
{
  __shared__ float s_gw[NEXP*DDIM];
  __shared__ float s_sums[NEXP];
  __shared__ float s_nw[NEXP];
  int tid = threadIdx.x;
  for (int i = tid; i < NEXP*DDIM/4; i += 128)
    ((f32x4*)s_gw)[i] = ((const f32x4*)gw)[i];
  if (tid < NEXP) { s_sums[tid] = 0.f; s_nw[tid] = nw[tid]; }
  __syncthreads();
  int t = blockIdx.x*128 + tid;
  float acc[NEXP];
  #pragma unroll
  for (int e = 0; e < NEXP; ++e) acc[e] = 0.f;
  const f32x4* xr = (const f32x4*)(x + (size_t)t*DDIM);
  for (int d4 = 0; d4 < DDIM/4; ++d4) {
    f32x4 xv = xr[d4];
    #pragma unroll
    for (int e = 0; e < NEXP; ++e) {
      f32x4 g = *(const f32x4*)&s_gw[e*DDIM + d4*4];
      acc[e] += xv.x*g.x + xv.y*g.y + xv.z*g.z + xv.w*g.w;
    }
  }
  float m = acc[0];
  #pragma unroll
  for (int e = 1; e < NEXP; ++e) m = fmaxf(m, acc[e]);
  float p[NEXP], s = 0.f;
  #pragma unroll
  for (int e = 0; e < NEXP; ++e) { p[e] = __expf(acc[e]-m); s += p[e]; }
  float inv = 1.f/s;
  #pragma unroll
  for (int e = 0; e < NEXP; ++e) atomicAdd(&s_sums[e], p[e]*inv);
  float ln[NEXP];
  #pragma unroll
  for (int e = 0; e < NEXP; ++e) ln[e] = acc[e] + noise[(size_t)t*NEXP+e]*s_nw[e];
  int i0 = 0; float v0 = ln[0];
  #pragma unroll
  for (int e = 1; e < NEXP; ++e) if (ln[e] > v0) { v0 = ln[e]; i0 = e; }
  int i1 = -1; float v1 = 0.f;
  #pragma unroll
  for (int e = 0; e < NEXP; ++e)
    if (e != i0 && (i1 < 0 || ln[e] > v1)) { v1 = ln[e]; i1 = e; }
  float e1 = __expf(v1 - v0);
  float g0 = 1.f/(1.f + e1);
  float g1 = e1*g0;
  int p0 = atomicAdd(&counts[i0], 1);
  tok_list[i0*NTOK + p0] = t; gate_list[i0*NTOK + p0] = g0;
  int p1 = atomicAdd(&counts[i1], 1);
  tok_list[i1*NTOK + p1] = t; gate_list[i1*NTOK + p1] = g1;
  tok_top[2*t] = i0; tok_top[2*t+1] = i1;
  gate_top[2*t] = g0; gate_top[2*t+1] = g1;
  pos_top[2*t] = p0; pos_top[2*t+1] = p1;
  __syncthreads();
  if (tid < NEXP) atomicAdd(&sums[tid], s_sums[tid]);
}

// ---------------- offsets prefix + load-balance loss ----------------
__global__ void finalize_kernel(const int* counts, const float* sums,
                                int* offsets, float* loss_out)
{
  if (threadIdx.x == 0) {
    int o = 0;
    #pragma unroll
    for (int e = 0; e < NEXP; ++e) { offsets[e] = o; o += counts[e]; }
    offsets[NEXP] = o;
    float l = 0.f;
    #pragma unroll
    for (int e = 0; e < NEXP; ++e) {
      float dv = sums[e]*(1.f/(float)NTOK) - 1.f/(float)NEXP;
      l += dv*dv;
    }
    loss_out[0] = l*(0.01f/(float)NEXP);
  }
}

// ---------------- x -> bf16 ----------------
__global__ __launch_bounds__(256) void cvt_x_kernel(const float* __restrict__ x,
                                                    unsigned short* __restrict__ xb)
{
  int i = blockIdx.x*256 + threadIdx.x;
  f32x4 v = ((const f32x4*)x)[i];
  u16x4 o; o.x = f2bf(v.x); o.y = f2bf(v.y); o.z = f2bf(v.z); o.w = f2bf(v.w);
  ((u16x4*)xb)[i] = o;
}

// -------- transpose+convert pair: z<NEXP -> (src1,dst1), else (src2,dst2) -------
__global__ __launch_bounds__(256) void transpose_cvt2_kernel(
    const float* __restrict__ src1, unsigned short* __restrict__ dst1,
    const float* __restrict__ src2, unsigned short* __restrict__ dst2,
    int R, int C)
{
  __shared__ unsigned short s[64*65];
  int z = blockIdx.z;
  int e = z & (NEXP-1);
  const float* src = (z < NEXP) ? src1 : src2;
  unsigned short* dst = (z < NEXP) ? dst1 : dst2;
  int r0 = blockIdx.y*64, c0 = blockIdx.x*64;
  const float* sp = src + ((size_t)e*R + r0)*C + c0;
  unsigned short* dp = dst + ((size_t)e*C + c0)*R + r0;
  int t = threadIdx.x;
  #pragma unroll
  for (int i = 0; i < 16; ++i) {
    int idx = t + 256*i;
    int r = idx >> 6, c = idx & 63;
    s[c*65 + r] = f2bf(sp[(size_t)r*C + c]);
  }
  __syncthreads();
  #pragma unroll
  for (int i = 0; i < 16; ++i) {
    int idx = t + 256*i;
    int c = idx >> 6, r = idx & 63;
    dp[(size_t)c*R + r] = s[c*65 + r];
  }
}

__global__ __launch_bounds__(256) void transpose_cvt_kernel(
    const float* __restrict__ src, unsigned short* __restrict__ dst, int R, int C)
{
  __shared__ unsigned short s[64*65];
  int e = blockIdx.z;
  int r0 = blockIdx.y*64, c0 = blockIdx.x*64;
  const float* sp = src + ((size_t)e*R + r0)*C + c0;
  unsigned short* dp = dst + ((size_t)e*C + c0)*R + r0;
  int t = threadIdx.x;
  #pragma unroll
  for (int i = 0; i < 16; ++i) {
    int idx = t + 256*i;
    int r = idx >> 6, c = idx & 63;
    s[c*65 + r] = f2bf(sp[(size_t)r*C + c]);
  }
  __syncthreads();
  #pragma unroll
  for (int i = 0; i < 16; ++i) {
    int idx = t + 256*i;
    int c = idx >> 6, r = idx & 63;
    dp[(size_t)c*R + r] = s[c*65 + r];
  }
}

// ---------------- compact per-expert lists into M=16384 rows ----------------
__global__ __launch_bounds__(256) void compact_kernel(
    const int* __restrict__ counts, const int* __restrict__ offsets,
    const int* __restrict__ tok_list, const float* __restrict__ gate_list,
    int* __restrict__ row_token, float* __restrict__ row_gate)
{
  int e = blockIdx.y;
  int pos = blockIdx.x*256 + threadIdx.x;
  if (pos < counts[e]) {
    int r = offsets[e] + pos;
    row_token[r] = tok_list[e*NTOK + pos];
    row_gate[r]  = gate_list[e*NTOK + pos];
  }
}

// ---------------- y init with gated biases (tier B/C only) ----------------
__global__ __launch_bounds__(256) void init_y_kernel(
    const int* __restrict__ tok_top, const float* __restrict__ gate_top,
    const float* __restrict__ bp, float* __restrict__ y)
{
  int i = blockIdx.x*256 + threadIdx.x;
  int t = i / (DDIM/4);
  int d4 = i % (DDIM/4);
  int e0 = tok_top[2*t], e1 = tok_top[2*t+1];
  float g0 = gate_top[2*t], g1 = gate_top[2*t+1];
  f32x4 b0 = ((const f32x4*)(bp + (size_t)e0*DDIM))[d4];
  f32x4 b1v = ((const f32x4*)(bp + (size_t)e1*DDIM))[d4];
  ((f32x4*)y)[i] = g0*b0 + g1*b1v;
}

// ---------------- FFN1: 128 rows x 64 h-cols (both mats), BK=32 ----------------
// XCD-affine 1D grid: blockIdx.x & 7 = expert (one expert per XCD -> its A rows
// ~3.1MB stay hot in that XCD's 4MB L2). s>>5 = col-group (B tile shared by the
// 32 concurrently-resident row-blocks of the XCD), s&31 = row-block, imbalance
// handled by rb += RBMAX loop. kseg XOR-swizzle: 8-way -> 4-way LDS banks.
__global__ __launch_bounds__(256) void ffn1_mfma(
    const unsigned short* __restrict__ xb,
    const unsigned short* __restrict__ w1T, const unsigned short* __restrict__ w2T,
    const float* __restrict__ b1, const float* __restrict__ b2,
    const int* __restrict__ offsets, const int* __restrict__ row_token,
    unsigned short* __restrict__ h_buf, int h_base, int HC)
{
  int id = blockIdx.x;
  int e = id & 7;
  int s = id >> 3;
  int rb0 = s & (RBMAX-1);
  int cg = s >> 5;
  int r_lo = offsets[e];
  int rows_e = offsets[e+1] - r_lo;
  int h0 = h_base + cg*64;

  __shared__ __align__(16) char sA[8192];
  __shared__ __align__(16) char sB[8192];
  __shared__ int s_tok[128];

  int tid = threadIdx.x;
  int lane = tid & 63, w = tid >> 6;
  int l16 = lane & 15, quad = lane >> 4;
  int lr = lane >> 2, ls = lane & 3;
  int kseg = ls ^ (lr & 3);
  int fro = l16*64 + ((quad ^ (l16 & 3)) << 4);

  int colB = h0 + w*16 + lr;
  const unsigned short* gB1 = w1T + ((size_t)e*HDIM + colB)*DDIM + kseg*8;
  const unsigned short* gB2 = w2T + ((size_t)e*HDIM + colB)*DDIM + kseg*8;
  char* lA0 = sA + w*1024;
  char* lA1 = sA + (w+4)*1024;
  char* lB1 = sB + w*1024;
  char* lB2 = sB + (w+4)*1024;

  int hcol = h0 + w*16 + l16;
  float bb1 = b1[(size_t)e*HDIM + hcol];
  float bb2 = b2[(size_t)e*HDIM + hcol];
  int hl = hcol - h_base;

  for (int rb = rb0; rb*128 < rows_e; rb += RBMAX) {
    int r0 = r_lo + rb*128;
    int rows_valid = rows_e - rb*128; if (rows_valid > 128) rows_valid = 128;
    __syncthreads();
    if (tid < 128) {
      int r = r0 + tid; if (r > MROWS-1) r = MROWS-1;
      s_tok[tid] = row_token[r];
    }
    __syncthreads();
    const unsigned short* gA0 = xb + (size_t)s_tok[w*16 + lr]*DDIM + kseg*8;
    const unsigned short* gA1 = xb + (size_t)s_tok[(w+4)*16 + lr]*DDIM + kseg*8;

    f32x4 acc1[8], acc2[8];
    #pragma unroll
    for (int i = 0; i < 8; ++i) { acc1[i] = (f32x4){0,0,0,0}; acc2[i] = (f32x4){0,0,0,0}; }

    for (int k0 = 0; k0 < DDIM; k0 += 32) {
      async16(gA0 + k0, lA0);
      async16(gA1 + k0, lA1);
      async16(gB1 + k0, lB1);
      async16(gB2 + k0, lB2);
      __syncthreads();
      bf16x8 bf1 = *(const bf16x8*)(sB + w*1024 + fro);
      bf16x8 bf2 = *(const bf16x8*)(sB + (w+4)*1024 + fro);
      #pragma unroll
      for (int mt = 0; mt < 8; ++mt) {
        bf16x8 af = *(const bf16x8*)(sA + mt*1024 + fro);
        acc1[mt] = __builtin_amdgcn_mfma_f32_16x16x32_bf16(af, bf1, acc1[mt], 0, 0, 0);
        acc2[mt] = __builtin_amdgcn_mfma_f32_16x16x32_bf16(af, bf2, acc2[mt], 0, 0, 0);
      }
      __syncthreads();
    }
    // SwiGLU epilogue; C/D layout: col=lane&15, row=quad*4+reg
    #pragma unroll
    for (int mt = 0; mt < 8; ++mt) {
      #pragma unroll
      for (int r = 0; r < 4; ++r) {
        int row = mt*16 + quad*4 + r;
        if (row < rows_valid) {
          float c1 = acc1[mt][r] + bb1;
          float c2 = acc2[mt][r] + bb2;
          float hv = c1 * (c2 / (1.f + __expf(-c2)));
          h_buf[(size_t)(r0 + row)*HC + hl] = f2bf(hv);
        }
      }
    }
  }
}

// ---------------- FFN2: 128 rows x 128 d-cols, BK=32, XCD-affine ---------------
// mode 0: store raw h@wp into part[M][DDIM]. mode 1: atomicAdd gated into y.
__global__ __launch_bounds__(256) void ffn2_mfma(
    const unsigned short* __restrict__ h_buf, const unsigned short* __restrict__ wpT,
    const int* __restrict__ offsets, const int* __restrict__ row_token,
    const float* __restrict__ row_gate, float* __restrict__ outp,
    int h_base, int HC, int mode)
{
  int id = blockIdx.x;
  int e = id & 7;
  int s = id >> 3;
  int rb0 = s & (RBMAX-1);
  int cb = s >> 5;                 // 0..5
  int r_lo = offsets[e];
  int rows_e = offsets[e+1] - r_lo;
  int c0 = cb*128;

  __shared__ __align__(16) char sA[8192];
  __shared__ __align__(16) char sB[8192];
  __shared__ int s_tok[128];
  __shared__ float s_gate[128];

  int tid = threadIdx.x;
  int lane = tid & 63, w = tid >> 6;
  int l16 = lane & 15, quad = lane >> 4;
  int lr = lane >> 2, ls = lane & 3;
  int kseg = ls ^ (lr & 3);
  int fro = l16*64 + ((quad ^ (l16 & 3)) << 4);
  int wr = w & 1, wcg = w >> 1;

  const unsigned short* gB0 = wpT + ((size_t)e*DDIM + c0 + w*16 + lr)*HDIM + h_base + kseg*8;
  const unsigned short* gB1 = wpT + ((size_t)e*DDIM + c0 + (w+4)*16 + lr)*HDIM + h_base + kseg*8;
  char* lA0 = sA + w*1024;
  char* lA1 = sA + (w+4)*1024;
  char* lB0 = sB + w*1024;
  char* lB1 = sB + (w+4)*1024;

  for (int rb = rb0; rb*128 < rows_e; rb += RBMAX) {
    int r0 = r_lo + rb*128;
    int rows_valid = rows_e - rb*128; if (rows_valid > 128) rows_valid = 128;
    __syncthreads();
    if (tid < 128) {
      int r = r0 + tid; if (r > MROWS-1) r = MROWS-1;
      s_tok[tid]  = row_token[r];
      s_gate[tid] = row_gate[r];
    }
    __syncthreads();
    int rA0 = r0 + w*16 + lr;     if (rA0 > MROWS-1) rA0 = MROWS-1;
    int rA1 = r0 + (w+4)*16 + lr; if (rA1 > MROWS-1) rA1 = MROWS-1;
    const unsigned short* gA0 = h_buf + (size_t)rA0*HC + kseg*8;
    const unsigned short* gA1 = h_buf + (size_t)rA1*HC + kseg*8;

    f32x4 acc[4][4];
    #pragma unroll
    for (int i = 0; i < 4; ++i)
      #pragma unroll
      for (int j = 0; j < 4; ++j) acc[i][j] = (f32x4){0,0,0,0};

    for (int k0 = 0; k0 < HC; k0 += 32) {
      async16(gA0 + k0, lA0);
      async16(gA1 + k0, lA1);
      async16(gB0 + k0, lB0);
      async16(gB1 + k0, lB1);
      __syncthreads();
      bf16x8 bfr[4];
      #pragma unroll
      for (int nt = 0; nt < 4; ++nt)
        bfr[nt] = *(const bf16x8*)(sB + (wcg*4 + nt)*1024 + fro);
      #pragma unroll
      for (int mt = 0; mt < 4; ++mt) {
        bf16x8 af = *(const bf16x8*)(sA + (wr*4 + mt)*1024 + fro);
        #pragma unroll
        for (int nt = 0; nt < 4; ++nt)
          acc[mt][nt] = __builtin_amdgcn_mfma_f32_16x16x32_bf16(af, bfr[nt], acc[mt][nt], 0, 0, 0);
      }
      __syncthreads();
    }

    if (mode == 0) {
      #pragma unroll
      for (int nt = 0; nt < 4; ++nt) {
        int col = c0 + wcg*64 + nt*16 + l16;
        #pragma unroll
        for (int mt = 0; mt < 4; ++mt) {
          #pragma unroll
          for (int r = 0; r < 4; ++r) {
            int row = wr*64 + mt*16 + quad*4 + r;
            if (row < rows_valid)
              outp[(size_t)(r0 + row)*DDIM + col] = acc[mt][nt][r];
          }
        }
      }
    } else {
      #pragma unroll
      for (int nt = 0; nt < 4; ++nt) {
        int col = c0 + wcg*64 + nt*16 + l16;
        #pragma unroll
        for (int mt = 0; mt < 4; ++mt) {
          #pragma unroll
          for (int r = 0; r < 4; ++r) {
            int row = wr*64 + mt*16 + quad*4 + r;
            if (row < rows_valid)
              atomicAdd(&outp[(size_t)s_tok[row]*DDIM + col], s_gate[row]*acc[mt][nt][r]);
          }
        }
      }
    }
  }
}

// ---------------- combine (tier A): y = sum_i g_i*(part[row_i] + bp[e_i]) ------
__global__ __launch_bounds__(256) void combine_kernel(
    const float* __restrict__ part, const int* __restrict__ tok_top,
    const float* __restrict__ gate_top, const int* __restrict__ pos_top,
    const int* __restrict__ offsets, const float* __restrict__ bp,
    float* __restrict__ y)
{
  int i = blockIdx.x*256 + threadIdx.x;
  int t = i / (DDIM/4);
  int d4 = i % (DDIM/4);
  int e0 = tok_top[2*t], e1 = tok_top[2*t+1];
  float g0 = gate_top[2*t], g1 = gate_top[2*t+1];
  int r0 = offsets[e0] + pos_top[2*t];
  int r1 = offsets[e1] + pos_top[2*t+1];
  f32x4 v0 = ((const f32x4*)part)[(size_t)r0*(DDIM/4) + d4];
  f32x4 v1 = ((const f32x4*)part)[(size_t)r1*(DDIM/4) + d4];
  f32x4 b0 = ((const f32x4*)(bp + (size_t)e0*DDIM))[d4];
  f32x4 b1v = ((const f32x4*)(bp + (size_t)e1*DDIM))[d4];
  ((f32x4*)y)[i] = g0*(v0 + b0) + g1*(v1 + b1v);
}

// ---------------- legacy FFN2 (fp32 B direct) — tier C -------------------------
__global__ __launch_bounds__(256) void ffn2_kernel(
    const unsigned short* __restrict__ h_buf, const float* __restrict__ wp,
    const int* __restrict__ offsets, const int* __restrict__ row_token,
    const float* __restrict__ row_gate, float* __restrict__ y, int h_base, int HC)
{
  int e = blockIdx.z;
  int r_lo = offsets[e];
  int rows_e = offsets[e+1] - r_lo;
  int bx = blockIdx.x;
  if (bx*128 >= rows_e) return;
  int r0 = r_lo + bx*128;
  int rows_valid = rows_e - bx*128; if (rows_valid > 128) rows_valid = 128;
  int c0 = blockIdx.y*128;

  __shared__ unsigned short sA[128*40];
  __shared__ int s_tok[128];
  __shared__ float s_gate[128];

  int tid = threadIdx.x;
  if (tid < 128) {
    int r = r0 + tid; if (r > MROWS-1) r = MROWS-1;
    s_tok[tid]  = row_token[r];
    s_gate[tid] = row_gate[r];
  }
  int lane = tid & 63;
  int wc = tid >> 6;
  int quad = lane >> 4, l16 = lane & 15;

  const float* wp0 = wp + (size_t)e*HDIM*DDIM + c0 + wc*32 + l16;

  f32x4 acc[8][2];
  #pragma unroll
  for (int i = 0; i < 8; ++i) { acc[i][0] = (f32x4){0,0,0,0}; acc[i][1] = (f32x4){0,0,0,0}; }
  __syncthreads();

  for (int k0 = 0; k0 < HC; k0 += 32) {
    #pragma unroll
    for (int i = 0; i < 2; ++i) {
      int c = i*256 + tid;
      int row = c >> 2, k8 = c & 3;
      int rr = r0 + row; if (rr > MROWS-1) rr = MROWS-1;
      bf16x8 v = *(const bf16x8*)(h_buf + (size_t)rr*HC + k0 + k8*8);
      *(bf16x8*)&sA[row*40 + k8*8] = v;
    }
    float bv[2][8];
    #pragma unroll
    for (int nt = 0; nt < 2; ++nt)
      #pragma unroll
      for (int j = 0; j < 8; ++j)
        bv[nt][j] = wp0[(size_t)(h_base + k0 + quad*8 + j)*DDIM + nt*16];
    bf16x8 bfr[2];
    #pragma unroll
    for (int nt = 0; nt < 2; ++nt)
      #pragma unroll
      for (int j = 0; j < 8; ++j) bfr[nt][j] = (short)f2bf(bv[nt][j]);
    __syncthreads();
    #pragma unroll
    for (int mt = 0; mt < 8; ++mt) {
      bf16x8 af = *(const bf16x8*)&sA[(mt*16 + l16)*40 + quad*8];
      acc[mt][0] = __builtin_amdgcn_mfma_f32_16x16x32_bf16(af, bfr[0], acc[mt][0], 0, 0, 0);
      acc[mt][1] = __builtin_amdgcn_mfma_f32_16x16x32_bf16(af, bfr[1], acc[mt][1], 0, 0, 0);
    }
    __syncthreads();
  }
  #pragma unroll
  for (int nt = 0; nt < 2; ++nt) {
    int col = c0 + wc*32 + nt*16 + l16;
    #pragma unroll
    for (int mt = 0; mt < 8; ++mt) {
      #pragma unroll
      for (int r = 0; r < 4; ++r) {
        int row = mt*16 + quad*4 + r;
        if (row < rows_valid)
          atomicAdd(&y[(size_t)s_tok[row]*DDIM + col], s_gate[row]*acc[mt][nt][r]);
      }
    }
  }
}

extern "C" void kernel_launch(void* const* d_in, const int* in_sizes, int n_in,
                              void* d_out, int out_size, void* d_ws, size_t ws_size,
                              hipStream_t stream)
{
  (void)in_sizes; (void)n_in; (void)out_size;
  const float* x     = (const float*)d_in[0];
  const float* gw    = (const float*)d_in[1];
  const float* nw    = (const float*)d_in[2];
  const float* noise = (const float*)d_in[3];
  const float* w1    = (const float*)d_in[4];
  const float* b1    = (const float*)d_in[5];
  const float* w2    = (const float*)d_in[6];
  const float* b2    = (const float*)d_in[7];
  const float* wp    = (const float*)d_in[8];
  const float* bp    = (const float*)d_in[9];
  float* y = (float*)d_out;

  char* ws = (char*)d_ws;
  int*   counts   = (int*)(ws + 0);
  float* sums     = (float*)(ws + 64);
  int*   offsets  = (int*)(ws + 128);
  size_t off = 256;
  int*   tok_list  = (int*)(ws + off);   off += (size_t)NEXP*NTOK*4;
  float* gate_list = (float*)(ws + off); off += (size_t)NEXP*NTOK*4;
  int*   tok_top   = (int*)(ws + off);   off += (size_t)NTOK*2*4;
  float* gate_top  = (float*)(ws + off); off += (size_t)NTOK*2*4;
  int*   pos_top   = (int*)(ws + off);   off += (size_t)NTOK*2*4;
  int*   row_token = (int*)(ws + off);   off += (size_t)MROWS*4;
  float* row_gate  = (float*)(ws + off); off += (size_t)MROWS*4;
  unsigned short* xb = (unsigned short*)(ws + off); off += (size_t)NTOK*DDIM*2;

  const size_t WT    = (size_t)NEXP*DDIM*HDIM*2;   // one transposed bf16 weight set
  const size_t HFULL = (size_t)MROWS*HDIM*2;       // full h_buf bf16
  const size_t PSZ   = (size_t)MROWS*DDIM*4;       // part f32

  unsigned short* w1T = (unsigned short*)(ws + off);
  unsigned short* w2T = (unsigned short*)(ws + off + WT);
  unsigned short* wpT = (unsigned short*)(ws + off + 2*WT);

  bool tierA = (off + 3*WT + HFULL + PSZ <= ws_size);
  bool haveP = (off + 3*WT + (size_t)MROWS*128*2 <= ws_size);
  size_t oH = off + (haveP ? 3*WT : 2*WT);

  int HC;
  unsigned short* h_buf;
  float* part = nullptr;
  if (tierA) {
    HC = HDIM;
    h_buf = (unsigned short*)(ws + off + 3*WT);
    part  = (float*)(ws + off + 3*WT + HFULL);
  } else {
    static const int hc_opts[6] = {3072, 1536, 768, 384, 192, 128};
    HC = 128;
    for (int i = 0; i < 6; ++i)
      if (oH + (size_t)MROWS*hc_opts[i]*2 <= ws_size) { HC = hc_opts[i]; break; }
    h_buf = (unsigned short*)(ws + oH);
  }

  hipMemsetAsync(d_ws, 0, 256, stream);
  cvt_x_kernel<<<NTOK*DDIM/1024, 256, 0, stream>>>(x, xb);
  transpose_cvt2_kernel<<<dim3(HDIM/64, DDIM/64, NEXP*2), 256, 0, stream>>>(
      w1, w1T, w2, w2T, DDIM, HDIM);
  if (haveP)
    transpose_cvt_kernel<<<dim3(DDIM/64, HDIM/64, NEXP), 256, 0, stream>>>(wp, wpT, HDIM, DDIM);

  gating_kernel<<<NTOK/128, 128, 0, stream>>>(x, gw, nw, noise, counts, sums,
                                              tok_list, gate_list, tok_top, gate_top, pos_top);
  finalize_kernel<<<1, 64, 0, stream>>>(counts, sums, offsets, y + (size_t)NTOK*DDIM);
  compact_kernel<<<dim3(NTOK/256, NEXP), 256, 0, stream>>>(counts, offsets, tok_list,
                                                           gate_list, row_token, row_gate);

  if (tierA) {
    ffn1_mfma<<<NEXP*(HDIM/64)*RBMAX, 256, 0, stream>>>(xb, w1T, w2T, b1, b2, offsets,
                                                        row_token, h_buf, 0, HC);
    ffn2_mfma<<<NEXP*(DDIM/128)*RBMAX, 256, 0, stream>>>(h_buf, wpT, offsets, row_token,
                                                         row_gate, part, 0, HC, 0);
    combine_kernel<<<NTOK*DDIM/1024, 256, 0, stream>>>(part, tok_top, gate_top, pos_top,
                                                       offsets, bp, y);
  } else {
    init_y_kernel<<<NTOK*DDIM/1024, 256, 0, stream>>>(tok_top, gate_top, bp, y);
    int nch = HDIM / HC;
    for (int c = 0; c < nch; ++c) {
      ffn1_mfma<<<NEXP*(HC/64)*RBMAX, 256, 0, stream>>>(xb, w1T, w2T, b1, b2, offsets,
                                                        row_token, h_buf, c*HC, HC);
      if (haveP)
        ffn2_mfma<<<NEXP*(DDIM/128)*RBMAX, 256, 0, stream>>>(h_buf, wpT, offsets, row_token,
                                                             row_gate, y, c*HC, HC, 1);
      else
        ffn2_kernel<<<dim3(128, DDIM/128, NEXP), 256, 0, stream>>>(h_buf, wp, offsets, row_token,
                                                                   row_gate, y, c*HC, HC);
    }
  }
}